// Round 1
// baseline (191.539 us; speedup 1.0000x reference)
//
#include <hip/hip_runtime.h>
#include <cstdint>
#include <cstddef>

// ---------------------------------------------------------------------------
// x = mean_i( softmax(q_i K^T / 16) ) @ h   with q = h@Wq, k = h@Wk
//   = sum_j c_j h_j,  c_j = (1/N) sum_i exp(e_ij)/l_i,  l_i = sum_j exp(e_ij)
// No N x N materialization. No max-subtraction needed (|e| < ~15 << 88).
//
// ws layout:
//   [0, 4MB)        q in bf16, MFMA-A-fragment-major
//   [4MB, 8MB)      k in bf16, MFMA-B-fragment-major (same index function)
//   [8MB, +32KB)    l_arr fp32[8192]
//   [8MB+32KB, ..)  c_arr fp32[8192]
//
// Fragment-major layout (per 32-row tile, 16 KB):
//   element (i, d) -> tile = i>>5, slot = (d>>4)*64 + (i&31) + 32*((d>>3)&1),
//   byte j = d&7   (i.e., [tile][a0][lane][8 bf16])
// This makes both q A-frag loads (global dwordx4) and k B-frag loads
// (lane-linear ds_read_b128) perfectly coalesced / conflict-free for
// v_mfma_f32_32x32x16_bf16 computing Q @ K^T.
// ---------------------------------------------------------------------------

#define N_ROWS 8192
#define DIM    256

typedef __bf16 bf16x8 __attribute__((ext_vector_type(8)));
typedef unsigned short u16x8 __attribute__((ext_vector_type(8)));
typedef float f32x16 __attribute__((ext_vector_type(16)));
typedef float f32x4  __attribute__((ext_vector_type(4)));

__device__ __forceinline__ uint16_t f2bf(float f) {
    uint32_t u = __float_as_uint(f);
    uint32_t r = (u + 0x7fffu + ((u >> 16) & 1u)) >> 16;   // RTN-even
    return (uint16_t)r;
}

// element offset (in bf16/u16 units) in fragment-major layout
__device__ __forceinline__ size_t frag_off(int i, int d) {
    int tile = i >> 5, il = i & 31;
    int a0 = d >> 4, hi = (d >> 3) & 1, j = d & 7;
    return (size_t)tile * 8192 + (size_t)((a0 * 64) + il + 32 * hi) * 8 + j;
}

// ---------------------------------------------------------------------------
// Kernel 1: q = (h @ Wq) * 1/16 (exact pow2 scale), k = h @ Wk, both bf16,
// written in fragment-major layout. 256 blocks: blockIdx = rowblock*2 + which.
// ---------------------------------------------------------------------------
__global__ __launch_bounds__(256) void proj_kernel(
        const float* __restrict__ h, const float* __restrict__ Wq,
        const float* __restrict__ Wk, uint16_t* __restrict__ qf,
        uint16_t* __restrict__ kf) {
    __shared__ alignas(16) uint16_t wlds[8 * 8 * 64 * 8];   // 64 KB: half of W^ in frag order
    const int tid = threadIdx.x;
    const int lane = tid & 63, wave = tid >> 6;
    const int which = blockIdx.x & 1;
    const int rb = blockIdx.x >> 1;
    const float* __restrict__ W = which ? Wk : Wq;
    uint16_t* __restrict__ dst = which ? kf : qf;
    const float scale = which ? 1.0f : 0.0625f;
    const int rowbase = rb * 64 + wave * 16;

    // A-fragments of h (16 rows x 256 k), fp32 -> bf16 on the fly, kept in regs
    bf16x8 afrag[8];
    {
        const int r = rowbase + (lane & 15);
        const float* hp = h + (size_t)r * DIM + ((lane >> 4) * 8);
#pragma unroll
        for (int a0 = 0; a0 < 8; a0++) {
            float4 f0 = *(const float4*)(hp + a0 * 32);
            float4 f1 = *(const float4*)(hp + a0 * 32 + 4);
            u16x8 f;
            f[0] = f2bf(f0.x); f[1] = f2bf(f0.y); f[2] = f2bf(f0.z); f[3] = f2bf(f0.w);
            f[4] = f2bf(f1.x); f[5] = f2bf(f1.y); f[6] = f2bf(f1.z); f[7] = f2bf(f1.w);
            afrag[a0] = __builtin_bit_cast(bf16x8, f);
        }
    }

    for (int p = 0; p < 2; p++) {
        __syncthreads();
        // stage half of W (coltiles p*8..p*8+7) into LDS in B-fragment order
        for (int s = tid; s < 4096; s += 256) {
            int ctl = s >> 9, a0 = (s >> 6) & 7, l = s & 63;
            int n = (p * 8 + ctl) * 16 + (l & 15);
            int kb = a0 * 32 + (l >> 4) * 8;
            u16x8 f;
#pragma unroll
            for (int j = 0; j < 8; j++) f[j] = f2bf(W[(size_t)(kb + j) * DIM + n]);
            *(u16x8*)&wlds[(size_t)s * 8] = f;
        }
        __syncthreads();
#pragma unroll
        for (int ctl = 0; ctl < 8; ctl++) {
            const int ct = p * 8 + ctl;
            f32x4 acc;
#pragma unroll
            for (int i = 0; i < 4; i++) acc[i] = 0.0f;
#pragma unroll
            for (int a0 = 0; a0 < 8; a0++) {
                bf16x8 bfrag = __builtin_bit_cast(bf16x8,
                    *(const u16x8*)&wlds[(size_t)((ctl * 8 + a0) * 64 + lane) * 8]);
                acc = __builtin_amdgcn_mfma_f32_16x16x32_bf16(afrag[a0], bfrag, acc, 0, 0, 0);
            }
            const int dcol = ct * 16 + (lane & 15);
            const int rbas = rowbase + ((lane >> 4) << 2);
#pragma unroll
            for (int reg = 0; reg < 4; reg++) {
                dst[frag_off(rbas + reg, dcol)] = f2bf(acc[reg] * scale);
            }
        }
    }
}

// ---------------------------------------------------------------------------
// Kernels 2/3: the two QK^T passes. MODE 0: row sums l_i. MODE 1: weighted
// column sums c_j. 512 blocks = 32 rowblocks(256 rows) x 16 colchunks(512).
// Wave = 64 rows (q resident in 128 VGPRs), k streamed 32 cols/step via LDS.
// ---------------------------------------------------------------------------
template <int MODE>
__global__ __launch_bounds__(256, 2) void pass_kernel(
        const uint16_t* __restrict__ qf, const uint16_t* __restrict__ kf,
        float* __restrict__ l_arr, float* __restrict__ c_arr) {
    __shared__ alignas(16) uint16_t ktile[8192];   // 32 cols x 256 d, frag-major (16 KB)
    __shared__ float c_lds[512];
    const int tid = threadIdx.x, lane = tid & 63, wave = tid >> 6;
    const int rb = blockIdx.x >> 4, cc = blockIdx.x & 15;
    const int t0 = rb * 8 + wave * 2;            // fragment tile of this wave's rowtile 0

    // resident q fragments: 2 rowtiles x 16 k-chunks
    bf16x8 qreg[2][16];
    {
        const uint4* qp = (const uint4*)qf;
#pragma unroll
        for (int rt = 0; rt < 2; rt++)
#pragma unroll
            for (int a0 = 0; a0 < 16; a0++) {
                uint4 u = qp[(size_t)(t0 + rt) * 1024 + a0 * 64 + lane];
                qreg[rt][a0] = __builtin_bit_cast(bf16x8, u);
            }
    }

    float rs[2][16];   // MODE 0: per-lane row-sum partials
    float rr[2][16];   // MODE 1: 1/(N*l_i) per (rt, reg)
    if (MODE == 0) {
#pragma unroll
        for (int rt = 0; rt < 2; rt++)
#pragma unroll
            for (int reg = 0; reg < 16; reg++) rs[rt][reg] = 0.0f;
    } else {
#pragma unroll
        for (int rt = 0; rt < 2; rt++)
#pragma unroll
            for (int reg = 0; reg < 16; reg++) {
                int row = rb * 256 + wave * 64 + rt * 32 + (reg & 3) + 8 * (reg >> 2) + 4 * (lane >> 5);
                rr[rt][reg] = 1.0f / (8192.0f * l_arr[row]);
            }
        for (int i = tid; i < 512; i += 256) c_lds[i] = 0.0f;
        __syncthreads();
    }

    // prefetch first k tile into registers
    uint4 stage[4];
    {
        const uint4* ksrc = (const uint4*)(kf + (size_t)(cc * 16) * 8192);
#pragma unroll
        for (int it = 0; it < 4; it++) stage[it] = ksrc[it * 256 + tid];
    }

    for (int step = 0; step < 16; step++) {
        __syncthreads();                               // LDS free from previous step
#pragma unroll
        for (int it = 0; it < 4; it++) ((uint4*)ktile)[it * 256 + tid] = stage[it];
        __syncthreads();
        if (step < 15) {                               // prefetch next tile (overlaps MFMA)
            const uint4* nsrc = (const uint4*)(kf + (size_t)(cc * 16 + step + 1) * 8192);
#pragma unroll
            for (int it = 0; it < 4; it++) stage[it] = nsrc[it * 256 + tid];
        }

        f32x16 acc0, acc1;
#pragma unroll
        for (int i = 0; i < 16; i++) { acc0[i] = 0.0f; acc1[i] = 0.0f; }
#pragma unroll
        for (int a0 = 0; a0 < 16; a0++) {
            bf16x8 bfrag = __builtin_bit_cast(bf16x8,
                *(const u16x8*)&ktile[(size_t)(a0 * 64 + lane) * 8]);
            acc0 = __builtin_amdgcn_mfma_f32_32x32x16_bf16(qreg[0][a0], bfrag, acc0, 0, 0, 0);
            acc1 = __builtin_amdgcn_mfma_f32_32x32x16_bf16(qreg[1][a0], bfrag, acc1, 0, 0, 0);
        }

        if (MODE == 0) {
#pragma unroll
            for (int reg = 0; reg < 16; reg++) {
                rs[0][reg] += __expf(acc0[reg]);
                rs[1][reg] += __expf(acc1[reg]);
            }
        } else {
            float s = 0.0f;
#pragma unroll
            for (int reg = 0; reg < 16; reg++) {
                s += __expf(acc0[reg]) * rr[0][reg];
                s += __expf(acc1[reg]) * rr[1][reg];
            }
            s += __shfl_xor(s, 32);                    // fold the two 32-lane row halves
            if (lane < 32) atomicAdd(&c_lds[step * 32 + lane], s);
        }
    }

    if (MODE == 0) {
#pragma unroll
        for (int rt = 0; rt < 2; rt++)
#pragma unroll
            for (int reg = 0; reg < 16; reg++) {
                float v = rs[rt][reg];
                v += __shfl_xor(v, 1);  v += __shfl_xor(v, 2);  v += __shfl_xor(v, 4);
                v += __shfl_xor(v, 8);  v += __shfl_xor(v, 16);
                if ((lane & 31) == 0) {
                    int row = rb * 256 + wave * 64 + rt * 32 + (reg & 3) + 8 * (reg >> 2) + 4 * (lane >> 5);
                    atomicAdd(&l_arr[row], v);
                }
            }
    } else {
        __syncthreads();
        for (int i = tid; i < 512; i += 256) atomicAdd(&c_arr[cc * 512 + i], c_lds[i]);
    }
}

// ---------------------------------------------------------------------------
// Kernel 4: x = c @ h  (8192 x 256, read-once)
// ---------------------------------------------------------------------------
__global__ __launch_bounds__(256) void finish_kernel(
        const float* __restrict__ h, const float* __restrict__ c_arr,
        float* __restrict__ out) {
    const int d = threadIdx.x;
    const int j0 = blockIdx.x * 128;
    float acc = 0.0f;
    for (int j = j0; j < j0 + 128; j++) acc += c_arr[j] * h[(size_t)j * DIM + d];
    atomicAdd(&out[d], acc);
}

// ---------------------------------------------------------------------------
extern "C" void kernel_launch(void* const* d_in, const int* in_sizes, int n_in,
                              void* d_out, int out_size, void* d_ws, size_t ws_size,
                              hipStream_t stream) {
    const float* h  = (const float*)d_in[0];
    const float* Wq = (const float*)d_in[1];
    const float* Wk = (const float*)d_in[2];

    uint16_t* qf = (uint16_t*)d_ws;
    uint16_t* kf = qf + (size_t)N_ROWS * DIM;                  // +4 MB
    float* l_arr = (float*)((char*)d_ws + (size_t)8 * 1024 * 1024);
    float* c_arr = l_arr + N_ROWS;
    float* out = (float*)d_out;

    hipMemsetAsync(l_arr, 0, N_ROWS * sizeof(float), stream);
    hipMemsetAsync(c_arr, 0, N_ROWS * sizeof(float), stream);
    hipMemsetAsync(out, 0, DIM * sizeof(float), stream);

    proj_kernel<<<256, 256, 0, stream>>>(h, Wq, Wk, qf, kf);
    pass_kernel<0><<<512, 256, 0, stream>>>(qf, kf, l_arr, c_arr);
    pass_kernel<1><<<512, 256, 0, stream>>>(qf, kf, l_arr, c_arr);
    finish_kernel<<<64, 256, 0, stream>>>(h, c_arr, out);
}

// Round 2
// 165.646 us; speedup vs baseline: 1.1563x; 1.1563x over previous
//
#include <hip/hip_runtime.h>
#include <cstdint>
#include <cstddef>

// ---------------------------------------------------------------------------
// x = mean_i( softmax(q_i K^T / 16) ) @ h   with q = h@Wq, k = h@Wk
//   = sum_j c_j h_j,  c_j = (1/N) sum_i exp(e_ij)/l_i,  l_i = sum_j exp(e_ij)
//
// Round 2: pass kernels restructured for occupancy + async staging.
//  - 4 blocks/CU (launch_bounds(256,4)), grid 1024 = 64 rowblocks x 16 colchunks
//  - each wave holds ONE 32-row q tile resident (64 VGPR), one f32x16 acc
//  - k staged via __builtin_amdgcn_global_load_lds (width 16), double-buffered,
//    ONE barrier per step; prefetch issued right after the barrier so it has
//    the whole compute phase to land (never drained by the barrier that
//    launched it)
//  - memsets folded into proj_kernel; finish parallelized to 256 blocks
//
// ws layout: [0,4MB) q bf16 frag-major | [4MB,8MB) k bf16 frag-major
//            [8MB) l_arr fp32[8192] | then c_arr fp32[8192]
// Fragment-major: elem (i,d) -> tile i>>5, slot (d>>4)*64 + (i&31) + 32*((d>>3)&1),
// byte j = d&7. Lane-linear 16B for both global dwordx4 and ds_read_b128.
// ---------------------------------------------------------------------------

#define N_ROWS 8192
#define DIM    256

typedef __bf16 bf16x8 __attribute__((ext_vector_type(8)));
typedef unsigned short u16x8 __attribute__((ext_vector_type(8)));
typedef float f32x16 __attribute__((ext_vector_type(16)));
typedef float f32x4  __attribute__((ext_vector_type(4)));

__device__ __forceinline__ uint16_t f2bf(float f) {
    uint32_t u = __float_as_uint(f);
    uint32_t r = (u + 0x7fffu + ((u >> 16) & 1u)) >> 16;   // RTN-even
    return (uint16_t)r;
}

// async global->LDS, 16B per lane; ldst is wave-uniform base, HW adds lane*16
__device__ __forceinline__ void gld16(const void* gsrc, void* ldst) {
    __builtin_amdgcn_global_load_lds(
        (const __attribute__((address_space(1))) unsigned int*)gsrc,
        (__attribute__((address_space(3))) unsigned int*)ldst, 16, 0, 0);
}

// element offset (bf16 units) in fragment-major layout
__device__ __forceinline__ size_t frag_off(int i, int d) {
    int tile = i >> 5, il = i & 31;
    int a0 = d >> 4, hi = (d >> 3) & 1, j = d & 7;
    return (size_t)tile * 8192 + (size_t)((a0 * 64) + il + 32 * hi) * 8 + j;
}

// ---------------------------------------------------------------------------
// Kernel 1: q = (h @ Wq) * 1/16, k = h @ Wk, bf16 frag-major.
// Also zero-inits l_arr / c_arr / out (replaces 3 memset dispatches).
// 256 blocks: blockIdx = rowblock*2 + which (128 rb x 64 rows).
// ---------------------------------------------------------------------------
__global__ __launch_bounds__(256) void proj_kernel(
        const float* __restrict__ h, const float* __restrict__ Wq,
        const float* __restrict__ Wk, uint16_t* __restrict__ qf,
        uint16_t* __restrict__ kf, float* __restrict__ l_arr,
        float* __restrict__ c_arr, float* __restrict__ out) {
    __shared__ alignas(16) uint16_t wlds[8 * 8 * 64 * 8];   // 64 KB
    const int tid = threadIdx.x;
    const int lane = tid & 63, wave = tid >> 6;
    const int which = blockIdx.x & 1;
    const int rb = blockIdx.x >> 1;

    // folded zero-init (runs before pass kernels via stream order)
    if (blockIdx.x < 32)       l_arr[blockIdx.x * 256 + tid] = 0.0f;
    else if (blockIdx.x < 64)  c_arr[(blockIdx.x - 32) * 256 + tid] = 0.0f;
    else if (blockIdx.x == 64) out[tid] = 0.0f;

    const float* __restrict__ W = which ? Wk : Wq;
    uint16_t* __restrict__ dst = which ? kf : qf;
    const float scale = which ? 1.0f : 0.0625f;
    const int rowbase = rb * 64 + wave * 16;

    // A-fragments of h (16 rows x 256 k), fp32 -> bf16, kept in regs
    bf16x8 afrag[8];
    {
        const int r = rowbase + (lane & 15);
        const float* hp = h + (size_t)r * DIM + ((lane >> 4) * 8);
#pragma unroll
        for (int a0 = 0; a0 < 8; a0++) {
            float4 f0 = *(const float4*)(hp + a0 * 32);
            float4 f1 = *(const float4*)(hp + a0 * 32 + 4);
            u16x8 f;
            f[0] = f2bf(f0.x); f[1] = f2bf(f0.y); f[2] = f2bf(f0.z); f[3] = f2bf(f0.w);
            f[4] = f2bf(f1.x); f[5] = f2bf(f1.y); f[6] = f2bf(f1.z); f[7] = f2bf(f1.w);
            afrag[a0] = __builtin_bit_cast(bf16x8, f);
        }
    }

    for (int p = 0; p < 2; p++) {
        __syncthreads();
        // stage half of W (coltiles p*8..p*8+7) into LDS in B-fragment order
        for (int s = tid; s < 4096; s += 256) {
            int ctl = s >> 9, a0 = (s >> 6) & 7, l = s & 63;
            int n = (p * 8 + ctl) * 16 + (l & 15);
            int kb = a0 * 32 + (l >> 4) * 8;
            u16x8 f;
#pragma unroll
            for (int j = 0; j < 8; j++) f[j] = f2bf(W[(size_t)(kb + j) * DIM + n]);
            *(u16x8*)&wlds[(size_t)s * 8] = f;
        }
        __syncthreads();
#pragma unroll
        for (int ctl = 0; ctl < 8; ctl++) {
            const int ct = p * 8 + ctl;
            f32x4 acc;
#pragma unroll
            for (int i = 0; i < 4; i++) acc[i] = 0.0f;
#pragma unroll
            for (int a0 = 0; a0 < 8; a0++) {
                bf16x8 bfrag = __builtin_bit_cast(bf16x8,
                    *(const u16x8*)&wlds[(size_t)((ctl * 8 + a0) * 64 + lane) * 8]);
                acc = __builtin_amdgcn_mfma_f32_16x16x32_bf16(afrag[a0], bfrag, acc, 0, 0, 0);
            }
            const int dcol = ct * 16 + (lane & 15);
            const int rbas = rowbase + ((lane >> 4) << 2);
#pragma unroll
            for (int reg = 0; reg < 4; reg++) {
                dst[frag_off(rbas + reg, dcol)] = f2bf(acc[reg] * scale);
            }
        }
    }
}

// ---------------------------------------------------------------------------
// Kernels 2/3: two QK^T passes. MODE 0: row sums l_i. MODE 1: weighted column
// sums c_j. Grid 1024 = 64 rowblocks(128 rows) x 16 colchunks(512 cols).
// Wave = 1 rowtile (32 rows, qreg 64 VGPR). k double-buffered via async
// global_load_lds, one barrier per 32-col step.
// ---------------------------------------------------------------------------
template <int MODE>
__global__ __launch_bounds__(256, 4) void pass_kernel(
        const uint16_t* __restrict__ qf, const uint16_t* __restrict__ kf,
        float* __restrict__ l_arr, float* __restrict__ c_arr) {
    __shared__ alignas(16) uint16_t ktile[2][8192];   // 2 x 16 KB double buffer
    __shared__ float c_lds[512];
    const int tid = threadIdx.x, lane = tid & 63, wave = tid >> 6;
    const int rb = blockIdx.x >> 4, cc = blockIdx.x & 15;
    const int t0 = rb * 4 + wave;                     // this wave's q fragment tile

    // resident q fragments: 1 rowtile x 16 k-chunks = 64 VGPRs
    bf16x8 qreg[16];
    {
        const uint4* qp = (const uint4*)qf;
#pragma unroll
        for (int a0 = 0; a0 < 16; a0++)
            qreg[a0] = __builtin_bit_cast(bf16x8, qp[(size_t)t0 * 1024 + a0 * 64 + lane]);
    }

    float rs[16];   // MODE 0: per-lane row-sum partials
    float rr[16];   // MODE 1: 1/(N*l_i) per reg
    if (MODE == 0) {
#pragma unroll
        for (int reg = 0; reg < 16; reg++) rs[reg] = 0.0f;
    } else {
#pragma unroll
        for (int reg = 0; reg < 16; reg++) {
            int row = rb * 128 + wave * 32 + (reg & 3) + 8 * (reg >> 2) + 4 * (lane >> 5);
            rr[reg] = 1.0f / (8192.0f * l_arr[row]);
        }
        for (int i = tid; i < 512; i += 256) c_lds[i] = 0.0f;
    }

    const char* ksrc = (const char*)(kf + (size_t)cc * 16 * 8192);  // 16 tiles x 16 KB

    // prologue: stage tile 0 -> buffer 0 (4 async 1KB wave-copies per wave)
    {
        const char* s0 = ksrc + wave * 4096 + lane * 16;
        char* d0 = (char*)&ktile[0][0] + wave * 4096;
#pragma unroll
        for (int it = 0; it < 4; it++) gld16(s0 + it * 1024, d0 + it * 1024);
    }

    for (int step = 0; step < 16; step++) {
        // drains vmcnt: tile `step` staged; all waves done reading other buffer
        __syncthreads();
        if (step < 15) {   // prefetch next tile into the other buffer
            const char* sn = ksrc + (step + 1) * 16384 + wave * 4096 + lane * 16;
            char* dn = (char*)&ktile[(step + 1) & 1][0] + wave * 4096;
#pragma unroll
            for (int it = 0; it < 4; it++) gld16(sn + it * 1024, dn + it * 1024);
        }

        const uint16_t* kt = &ktile[step & 1][0];
        f32x16 acc;
#pragma unroll
        for (int i = 0; i < 16; i++) acc[i] = 0.0f;
#pragma unroll
        for (int a0 = 0; a0 < 16; a0++) {
            bf16x8 bfrag = __builtin_bit_cast(bf16x8,
                *(const u16x8*)&kt[(size_t)(a0 * 64 + lane) * 8]);
            acc = __builtin_amdgcn_mfma_f32_32x32x16_bf16(qreg[a0], bfrag, acc, 0, 0, 0);
        }

        if (MODE == 0) {
#pragma unroll
            for (int reg = 0; reg < 16; reg++) rs[reg] += __expf(acc[reg]);
        } else {
            float s = 0.0f;
#pragma unroll
            for (int reg = 0; reg < 16; reg++) s += __expf(acc[reg]) * rr[reg];
            s += __shfl_xor(s, 32);                 // fold the two 32-lane row halves
            if (lane < 32) atomicAdd(&c_lds[step * 32 + lane], s);
        }
    }

    if (MODE == 0) {
#pragma unroll
        for (int reg = 0; reg < 16; reg++) {
            float v = rs[reg];
            v += __shfl_xor(v, 1);  v += __shfl_xor(v, 2);  v += __shfl_xor(v, 4);
            v += __shfl_xor(v, 8);  v += __shfl_xor(v, 16);
            if ((lane & 31) == 0) {
                int row = rb * 128 + wave * 32 + (reg & 3) + 8 * (reg >> 2) + 4 * (lane >> 5);
                atomicAdd(&l_arr[row], v);
            }
        }
    } else {
        __syncthreads();
        for (int i = tid; i < 512; i += 256) atomicAdd(&c_arr[cc * 512 + i], c_lds[i]);
    }
}

// ---------------------------------------------------------------------------
// Kernel 4: x = c @ h  (8192 x 256, read-once). 256 blocks x 32 rows.
// ---------------------------------------------------------------------------
__global__ __launch_bounds__(256) void finish_kernel(
        const float* __restrict__ h, const float* __restrict__ c_arr,
        float* __restrict__ out) {
    const int d = threadIdx.x;
    const int j0 = blockIdx.x * 32;
    float acc = 0.0f;
    for (int j = j0; j < j0 + 32; j++) acc += c_arr[j] * h[(size_t)j * DIM + d];
    atomicAdd(&out[d], acc);
}

// ---------------------------------------------------------------------------
extern "C" void kernel_launch(void* const* d_in, const int* in_sizes, int n_in,
                              void* d_out, int out_size, void* d_ws, size_t ws_size,
                              hipStream_t stream) {
    const float* h  = (const float*)d_in[0];
    const float* Wq = (const float*)d_in[1];
    const float* Wk = (const float*)d_in[2];

    uint16_t* qf = (uint16_t*)d_ws;
    uint16_t* kf = qf + (size_t)N_ROWS * DIM;                  // +4 MB
    float* l_arr = (float*)((char*)d_ws + (size_t)8 * 1024 * 1024);
    float* c_arr = l_arr + N_ROWS;
    float* out = (float*)d_out;

    proj_kernel<<<256, 256, 0, stream>>>(h, Wq, Wk, qf, kf, l_arr, c_arr, out);
    pass_kernel<0><<<1024, 256, 0, stream>>>(qf, kf, l_arr, c_arr);
    pass_kernel<1><<<1024, 256, 0, stream>>>(qf, kf, l_arr, c_arr);
    finish_kernel<<<256, 256, 0, stream>>>(h, c_arr, out);
}